// Round 9
// baseline (12471.793 us; speedup 1.0000x reference)
//
#include <hip/hip_runtime.h>
#include <math.h>

#define T_SEQ 4096
#define H_DIM 1024
#define G4    4096
#define NBLK  64      // scan blocks; each owns 16 h-lanes (64 gate rows)
#define NTHR  512
// dynamic LDS: 128KB bf16 weights + 4KB h + 256B xg + 256B dot
#define SCAN_LDS_BYTES (131072 + 4096 + 256 + 256)

// ---------------------------------------------------------------------------
// K1: xg[t][j] = dot(embedding[tokens[t]], w_ih[j]) + b_ih[j] + b_hh[j]
// fp32 GEMM, 128x128 tile, BK=16, 256 threads, 8x8 microtile.
// ---------------------------------------------------------------------------
__global__ __launch_bounds__(256) void xg_gemm(
    const int* __restrict__ tokens, const float* __restrict__ emb,
    const float* __restrict__ w_ih, const float* __restrict__ b_ih,
    const float* __restrict__ b_hh, float* __restrict__ xg)
{
    __shared__ float As[16][128];
    __shared__ float Bs[16][128];
    __shared__ int   tk[128];

    const int tid  = threadIdx.x;
    const int row0 = blockIdx.y * 128;
    const int col0 = blockIdx.x * 128;

    if (tid < 128) tk[tid] = tokens[row0 + tid];
    __syncthreads();

    const int r    = tid >> 1;
    const int half = tid & 1;
    const int tx   = tid & 15;
    const int ty   = tid >> 4;

    const float* ap_base = emb + (size_t)tk[r] * 1024 + half * 8;
    const float* bp_base = w_ih + (size_t)(col0 + r) * 1024 + half * 8;

    float acc[8][8] = {};

    for (int kc = 0; kc < 1024; kc += 16) {
        const float4 a0 = ((const float4*)(ap_base + kc))[0];
        const float4 a1 = ((const float4*)(ap_base + kc))[1];
        const float4 b0 = ((const float4*)(bp_base + kc))[0];
        const float4 b1 = ((const float4*)(bp_base + kc))[1];
        __syncthreads();
        const int kb = half * 8;
        As[kb+0][r] = a0.x; As[kb+1][r] = a0.y; As[kb+2][r] = a0.z; As[kb+3][r] = a0.w;
        As[kb+4][r] = a1.x; As[kb+5][r] = a1.y; As[kb+6][r] = a1.z; As[kb+7][r] = a1.w;
        Bs[kb+0][r] = b0.x; Bs[kb+1][r] = b0.y; Bs[kb+2][r] = b0.z; Bs[kb+3][r] = b0.w;
        Bs[kb+4][r] = b1.x; Bs[kb+5][r] = b1.y; Bs[kb+6][r] = b1.z; Bs[kb+7][r] = b1.w;
        __syncthreads();
        #pragma unroll
        for (int k = 0; k < 16; ++k) {
            const float4 a0v = *(const float4*)&As[k][ty*8];
            const float4 a1v = *(const float4*)&As[k][ty*8+4];
            const float4 b0v = *(const float4*)&Bs[k][tx*8];
            const float4 b1v = *(const float4*)&Bs[k][tx*8+4];
            const float aa[8] = {a0v.x,a0v.y,a0v.z,a0v.w,a1v.x,a1v.y,a1v.z,a1v.w};
            const float bb[8] = {b0v.x,b0v.y,b0v.z,b0v.w,b1v.x,b1v.y,b1v.z,b1v.w};
            #pragma unroll
            for (int ii = 0; ii < 8; ++ii)
                #pragma unroll
                for (int jj = 0; jj < 8; ++jj)
                    acc[ii][jj] = fmaf(aa[ii], bb[jj], acc[ii][jj]);
        }
    }

    const int ccol = col0 + tx * 8;
    float bs[8];
    #pragma unroll
    for (int jj = 0; jj < 8; ++jj) bs[jj] = b_ih[ccol + jj] + b_hh[ccol + jj];
    #pragma unroll
    for (int ii = 0; ii < 8; ++ii) {
        float* orow = xg + (size_t)(row0 + ty*8 + ii) * G4 + ccol;
        float4 o0, o1;
        o0.x = acc[ii][0] + bs[0]; o0.y = acc[ii][1] + bs[1];
        o0.z = acc[ii][2] + bs[2]; o0.w = acc[ii][3] + bs[3];
        o1.x = acc[ii][4] + bs[4]; o1.y = acc[ii][5] + bs[5];
        o1.z = acc[ii][6] + bs[6]; o1.w = acc[ii][7] + bs[7];
        ((float4*)orow)[0] = o0;
        ((float4*)orow)[1] = o1;
    }
}

// ---------------------------------------------------------------------------
// K2: persistent LSTM scan.  64 blocks x 512 threads; block b owns h-lanes
// {16b..16b+15}.  Weights bf16 in LDS (128 KB), rotation c=(i+j)&15 baked in
// (R7: conflict-free).  R8 lesson: per-thread data polling = agent-load storm
// (73% duty) that queues ahead of the publish stores at the coherence point,
// inflating propagation 0.15us (R5, quiet fabric) -> 1.6us.  New protocol:
//   publish: one per-lane tagged-msg store (tid<16) + lane0 done[b]=t+1
//   poll:    ONLY wave 0 polls done[] (lane l -> publisher l, 16 hot lines
//            grid-wide, read-shared); waves 1-7 wait at the hw barrier
//   sweep:   after detect, ONE tag-verified 8KB coalesced sweep (micro-retry
//            covers relaxed-ordering stragglers)
// Skew: publish precedes poll => max 1 step ahead; done check uses >=;
// 2-slot msg ring stays safe.
// ---------------------------------------------------------------------------
__device__ __forceinline__ float fsigmoid_(float x) {
    return 1.0f / (1.0f + __expf(-x));
}
__device__ __forceinline__ float ftanh_(float x) {
    x = fminf(fmaxf(x, -10.0f), 10.0f);
    const float e = __expf(2.0f * x);
    return (e - 1.0f) / (e + 1.0f);
}
__device__ __forceinline__ unsigned bf16rne_(float f) {   // finite inputs
    const unsigned u = __float_as_uint(f);
    return (u + 0x7FFFu + ((u >> 16) & 1u)) >> 16;
}
__device__ __forceinline__ float bf_lo_(unsigned u) {
    return __uint_as_float(u << 16);
}
__device__ __forceinline__ float bf_hi_(unsigned u) {
    return __uint_as_float(u & 0xFFFF0000u);
}

__global__ __launch_bounds__(NTHR, 1) void lstm_scan(
    const float* __restrict__ xg, const float* __restrict__ w_hh,
    const float* __restrict__ h0, const float* __restrict__ c0,
    unsigned long long* h_msg,           // [2][1024] {tag,bits}
    unsigned* done,                      // [64*4] publisher progress words
    float* __restrict__ h_fin, float* __restrict__ c_fin)
{
    extern __shared__ char smem[];
    unsigned* w_lds   = (unsigned*)smem;            // 32768 u32 (64 rows bf16)
    float*    h_lds   = (float*)(smem + 131072);    // 1024 f32
    float*    xg_lds  = h_lds + H_DIM;              // 64
    float*    dot_lds = xg_lds + 64;                // 64

    const int tid  = threadIdx.x;
    const int b    = blockIdx.x;
    const int lane = tid & 63;
    const int wv   = tid >> 6;           // wave 0..7
    const int r    = tid >> 3;           // gate-row within block 0..63
    const int j    = tid & 7;            // k-slice (128 floats)
    const int g    = r >> 4;             // gate 0..3
    const int m    = r & 15;             // h-lane within block
    const int grow = g * 1024 + 16 * b + m;

    // ---- stage weights: fp32 global -> bf16 packed; slot i holds global
    // chunk c=(i+j)&15 (rotation baked into storage)
    {
        const float* wsrc = w_hh + (size_t)grow * 1024 + j * 128;
        uint4* wdst = (uint4*)w_lds + (size_t)wv * 1024 + lane;
        #pragma unroll
        for (int i = 0; i < 16; ++i) {
            const int c = (i + j) & 15;
            const float4 a = ((const float4*)(wsrc + c * 8))[0];
            const float4 d = ((const float4*)(wsrc + c * 8))[1];
            uint4 u;
            u.x = bf16rne_(a.x) | (bf16rne_(a.y) << 16);
            u.y = bf16rne_(a.z) | (bf16rne_(a.w) << 16);
            u.z = bf16rne_(d.x) | (bf16rne_(d.y) << 16);
            u.w = bf16rne_(d.z) | (bf16rne_(d.w) << 16);
            wdst[i * 64] = u;
        }
    }

    float c_reg = 0.0f;
    if (tid < 16) c_reg = c0[16 * b + tid];

    // h version 0 from h0
    ((float2*)h_lds)[tid] = ((const float2*)h0)[tid];

    // prefetch xg for t=0 (tid<64 owns (gate=tid>>4, lane m=tid&15))
    float xc = 0.0f;
    if (tid < 64)
        xc = xg[(size_t)(tid >> 4) * 1024 + 16 * b + (tid & 15)];
    __syncthreads();

    const uint4*  wrd = (const uint4*)w_lds + (size_t)wv * 1024 + lane;
    const float4* h4  = (const float4*)h_lds + j * 32;

    // prime the weight registers (reloaded each iter during the sync window)
    uint4 wreg[16];
    #pragma unroll
    for (int i = 0; i < 16; ++i) wreg[i] = wrd[i * 64];

    for (int t = 0; t < T_SEQ; ++t) {
        // stage this step's xg into LDS; issue next step's prefetch
        if (tid < 64) {
            xg_lds[tid] = xc;
            if (t < T_SEQ - 1)
                xc = xg[(size_t)(t + 1) * G4 + (tid >> 4) * 1024 + 16 * b + (tid & 15)];
        }

        // 128-MAC partial dot: bf16 weights (registers) x fp32 h (LDS)
        float acc = 0.0f;
        #pragma unroll
        for (int i = 0; i < 16; ++i) {
            const int c = (i + j) & 15;
            const uint4  u  = wreg[i];
            const float4 ha = h4[2 * c];
            const float4 hb = h4[2 * c + 1];
            acc = fmaf(bf_lo_(u.x), ha.x, acc);
            acc = fmaf(bf_hi_(u.x), ha.y, acc);
            acc = fmaf(bf_lo_(u.y), ha.z, acc);
            acc = fmaf(bf_hi_(u.y), ha.w, acc);
            acc = fmaf(bf_lo_(u.z), hb.x, acc);
            acc = fmaf(bf_hi_(u.z), hb.y, acc);
            acc = fmaf(bf_lo_(u.w), hb.z, acc);
            acc = fmaf(bf_hi_(u.w), hb.w, acc);
        }
        acc += __shfl_xor(acc, 1);
        acc += __shfl_xor(acc, 2);
        acc += __shfl_xor(acc, 4);
        if (j == 0) dot_lds[r] = acc;
        __syncthreads();                                       // (A)

        // pointwise update + publish (one wave; per-lane msg store, then
        // lane0's done-word store — issued after the msg store instruction)
        if (tid < 16) {
            const float gi = xg_lds[tid]      + dot_lds[tid];
            const float gf = xg_lds[16 + tid] + dot_lds[16 + tid];
            const float gg = xg_lds[32 + tid] + dot_lds[32 + tid];
            const float go = xg_lds[48 + tid] + dot_lds[48 + tid];
            const float ii = fsigmoid_(gi);
            const float ff = fsigmoid_(gf);
            const float gt = ftanh_(gg);
            const float oo = fsigmoid_(go);
            c_reg = ff * c_reg + ii * gt;
            const float hn = oo * ftanh_(c_reg);
            const unsigned long long msg =
                ((unsigned long long)(unsigned)(t + 1) << 32) | __float_as_uint(hn);
            __hip_atomic_store(&h_msg[(size_t)((t + 1) & 1) * H_DIM + 16 * b + tid],
                               msg, __ATOMIC_RELAXED, __HIP_MEMORY_SCOPE_AGENT);
            if (tid == 0)
                __hip_atomic_store(&done[b * 4], (unsigned)(t + 1),
                                   __ATOMIC_RELAXED, __HIP_MEMORY_SCOPE_AGENT);
            if (t == T_SEQ - 1) {
                h_fin[16 * b + tid] = hn;
                c_fin[16 * b + tid] = c_reg;
            }
        }

        // re-issue weight loads for next iteration; latency hides under sync
        #pragma unroll
        for (int i = 0; i < 16; ++i) wreg[i] = wrd[i * 64];

        if (t < T_SEQ - 1) {
            const unsigned ver = (unsigned)(t + 1);

            // ---- detect: wave 0 only; lane l watches publisher l
            if (wv == 0) {
                const unsigned* dsrc = done + lane * 4;
                for (;;) {
                    const unsigned dv = __hip_atomic_load(
                        dsrc, __ATOMIC_RELAXED, __HIP_MEMORY_SCOPE_AGENT);
                    if (__all(dv >= ver)) break;
                }
            }
            __syncthreads();                                   // (B)

            // ---- single tag-verified sweep (2 msgs/thread, coalesced)
            const unsigned long long* src =
                h_msg + (size_t)(ver & 1) * H_DIM + 2 * tid;
            unsigned long long v0, v1;
            for (;;) {
                v0 = __hip_atomic_load(src + 0, __ATOMIC_RELAXED, __HIP_MEMORY_SCOPE_AGENT);
                v1 = __hip_atomic_load(src + 1, __ATOMIC_RELAXED, __HIP_MEMORY_SCOPE_AGENT);
                if (((unsigned)(v0 >> 32) == ver) & ((unsigned)(v1 >> 32) == ver))
                    break;   // rare: relaxed-ordering straggler
            }
            float2 hv;
            hv.x = __uint_as_float((unsigned)v0);
            hv.y = __uint_as_float((unsigned)v1);
            ((float2*)h_lds)[tid] = hv;
            __syncthreads();                                   // (C)
        }
    }
}

// ---------------------------------------------------------------------------
// K3: four 256x1024 mat-vec projections + bias.  One output per 32-lane group.
// ---------------------------------------------------------------------------
__global__ __launch_bounds__(256) void proj_kernel(
    const float* __restrict__ h_fin, const float* __restrict__ c_fin,
    const float* __restrict__ W_hm, const float* __restrict__ b_hm,
    const float* __restrict__ W_hv, const float* __restrict__ b_hv,
    const float* __restrict__ W_cm, const float* __restrict__ b_cm,
    const float* __restrict__ W_cv, const float* __restrict__ b_cv,
    float* __restrict__ out)
{
    const int tid = threadIdx.x;
    const int g32 = tid >> 5;
    const int j   = tid & 31;
    const int o   = blockIdx.x * 8 + g32;   // 0..1023
    const int mat = o >> 8;
    const int l   = o & 255;

    const float* W;  const float* bias;  const float* vec;
    if      (mat == 0) { W = W_hm; bias = b_hm; vec = h_fin; }
    else if (mat == 1) { W = W_hv; bias = b_hv; vec = h_fin; }
    else if (mat == 2) { W = W_cm; bias = b_cm; vec = c_fin; }
    else               { W = W_cv; bias = b_cv; vec = c_fin; }

    const float* wrow = W + (size_t)l * 1024;
    float acc = 0.0f;
    #pragma unroll
    for (int i = 0; i < 8; ++i) {
        const float4 wv = *(const float4*)(wrow + i * 128 + j * 4);
        const float4 xv = *(const float4*)(vec  + i * 128 + j * 4);
        acc += wv.x * xv.x + wv.y * xv.y + wv.z * xv.z + wv.w * xv.w;
    }
    acc += __shfl_xor(acc, 1);
    acc += __shfl_xor(acc, 2);
    acc += __shfl_xor(acc, 4);
    acc += __shfl_xor(acc, 8);
    acc += __shfl_xor(acc, 16);
    if (j == 0) out[o] = acc + bias[l];
}

// ---------------------------------------------------------------------------
extern "C" void kernel_launch(void* const* d_in, const int* in_sizes, int n_in,
                              void* d_out, int out_size, void* d_ws, size_t ws_size,
                              hipStream_t stream)
{
    const int*   tokens = (const int*)  d_in[0];
    const float* h0     = (const float*)d_in[1];
    const float* c0     = (const float*)d_in[2];
    const float* emb    = (const float*)d_in[3];
    const float* w_ih   = (const float*)d_in[4];
    const float* w_hh   = (const float*)d_in[5];
    const float* b_ih   = (const float*)d_in[6];
    const float* b_hh   = (const float*)d_in[7];
    const float* W_hm   = (const float*)d_in[8];
    const float* b_hm   = (const float*)d_in[9];
    const float* W_hv   = (const float*)d_in[10];
    const float* b_hv   = (const float*)d_in[11];
    const float* W_cm   = (const float*)d_in[12];
    const float* b_cm   = (const float*)d_in[13];
    const float* W_cv   = (const float*)d_in[14];
    const float* b_cv   = (const float*)d_in[15];
    float* out = (float*)d_out;

    char* ws = (char*)d_ws;
    float*              xg    = (float*)ws;            // T*4H fp32 = 64 MB
    size_t              off   = (size_t)T_SEQ * G4 * sizeof(float);
    unsigned long long* h_msg = (unsigned long long*)(ws + off);
    off += 2 * H_DIM * sizeof(unsigned long long);     // 16 KB
    unsigned* done = (unsigned*)(ws + off); off += 64 * 4 * sizeof(unsigned);
    float* h_fin = (float*)(ws + off); off += H_DIM * sizeof(float);
    float* c_fin = (float*)(ws + off); off += H_DIM * sizeof(float);

    // allow 132.6 KB dynamic LDS for the scan kernel (host attr, capture-safe)
    hipFuncSetAttribute((const void*)lstm_scan,
                        hipFuncAttributeMaxDynamicSharedMemorySize,
                        SCAN_LDS_BYTES);

    // clear stale tags + progress words (part of the captured graph)
    hipMemsetAsync(h_msg, 0xFF, 2 * H_DIM * sizeof(unsigned long long), stream);
    hipMemsetAsync(done, 0, 64 * 4 * sizeof(unsigned), stream);

    xg_gemm<<<dim3(32, 32), 256, 0, stream>>>(tokens, emb, w_ih, b_ih, b_hh, xg);
    lstm_scan<<<NBLK, NTHR, SCAN_LDS_BYTES, stream>>>(xg, w_hh, h0, c0, h_msg,
                                                      done, h_fin, c_fin);
    proj_kernel<<<128, 256, 0, stream>>>(h_fin, c_fin, W_hm, b_hm, W_hv, b_hv,
                                         W_cm, b_cm, W_cv, b_cv, out);
}

// Round 10
// 9448.448 us; speedup vs baseline: 1.3200x; 1.3200x over previous
//
#include <hip/hip_runtime.h>
#include <math.h>

#define T_SEQ 4096
#define H_DIM 1024
#define G4    4096
#define NBLK  64      // scan blocks; each owns 16 h-lanes (64 gate rows)
#define NTHR  512
#define NREP  8       // replicated mailbox regions (one per XCD-ish group)
// dynamic LDS: 128KB bf16 weights + 4KB h + 256B xg + 256B dot
#define SCAN_LDS_BYTES (131072 + 4096 + 256 + 256)

// ---------------------------------------------------------------------------
// K1: xg[t][j] = dot(embedding[tokens[t]], w_ih[j]) + b_ih[j] + b_hh[j]
// fp32 GEMM, 128x128 tile, BK=16, 256 threads, 8x8 microtile.
// ---------------------------------------------------------------------------
__global__ __launch_bounds__(256) void xg_gemm(
    const int* __restrict__ tokens, const float* __restrict__ emb,
    const float* __restrict__ w_ih, const float* __restrict__ b_ih,
    const float* __restrict__ b_hh, float* __restrict__ xg)
{
    __shared__ float As[16][128];
    __shared__ float Bs[16][128];
    __shared__ int   tk[128];

    const int tid  = threadIdx.x;
    const int row0 = blockIdx.y * 128;
    const int col0 = blockIdx.x * 128;

    if (tid < 128) tk[tid] = tokens[row0 + tid];
    __syncthreads();

    const int r    = tid >> 1;
    const int half = tid & 1;
    const int tx   = tid & 15;
    const int ty   = tid >> 4;

    const float* ap_base = emb + (size_t)tk[r] * 1024 + half * 8;
    const float* bp_base = w_ih + (size_t)(col0 + r) * 1024 + half * 8;

    float acc[8][8] = {};

    for (int kc = 0; kc < 1024; kc += 16) {
        const float4 a0 = ((const float4*)(ap_base + kc))[0];
        const float4 a1 = ((const float4*)(ap_base + kc))[1];
        const float4 b0 = ((const float4*)(bp_base + kc))[0];
        const float4 b1 = ((const float4*)(bp_base + kc))[1];
        __syncthreads();
        const int kb = half * 8;
        As[kb+0][r] = a0.x; As[kb+1][r] = a0.y; As[kb+2][r] = a0.z; As[kb+3][r] = a0.w;
        As[kb+4][r] = a1.x; As[kb+5][r] = a1.y; As[kb+6][r] = a1.z; As[kb+7][r] = a1.w;
        Bs[kb+0][r] = b0.x; Bs[kb+1][r] = b0.y; Bs[kb+2][r] = b0.z; Bs[kb+3][r] = b0.w;
        Bs[kb+4][r] = b1.x; Bs[kb+5][r] = b1.y; Bs[kb+6][r] = b1.z; Bs[kb+7][r] = b1.w;
        __syncthreads();
        #pragma unroll
        for (int k = 0; k < 16; ++k) {
            const float4 a0v = *(const float4*)&As[k][ty*8];
            const float4 a1v = *(const float4*)&As[k][ty*8+4];
            const float4 b0v = *(const float4*)&Bs[k][tx*8];
            const float4 b1v = *(const float4*)&Bs[k][tx*8+4];
            const float aa[8] = {a0v.x,a0v.y,a0v.z,a0v.w,a1v.x,a1v.y,a1v.z,a1v.w};
            const float bb[8] = {b0v.x,b0v.y,b0v.z,b0v.w,b1v.x,b1v.y,b1v.z,b1v.w};
            #pragma unroll
            for (int ii = 0; ii < 8; ++ii)
                #pragma unroll
                for (int jj = 0; jj < 8; ++jj)
                    acc[ii][jj] = fmaf(aa[ii], bb[jj], acc[ii][jj]);
        }
    }

    const int ccol = col0 + tx * 8;
    float bs[8];
    #pragma unroll
    for (int jj = 0; jj < 8; ++jj) bs[jj] = b_ih[ccol + jj] + b_hh[ccol + jj];
    #pragma unroll
    for (int ii = 0; ii < 8; ++ii) {
        float* orow = xg + (size_t)(row0 + ty*8 + ii) * G4 + ccol;
        float4 o0, o1;
        o0.x = acc[ii][0] + bs[0]; o0.y = acc[ii][1] + bs[1];
        o0.z = acc[ii][2] + bs[2]; o0.w = acc[ii][3] + bs[3];
        o1.x = acc[ii][4] + bs[4]; o1.y = acc[ii][5] + bs[5];
        o1.z = acc[ii][6] + bs[6]; o1.w = acc[ii][7] + bs[7];
        ((float4*)orow)[0] = o0;
        ((float4*)orow)[1] = o1;
    }
}

// ---------------------------------------------------------------------------
// K2: persistent LSTM scan.  64 blocks x 512 threads; block b owns h-lanes
// {16b..16b+15}.  Weights bf16 in LDS (128 KB), rotation c=(i+j)&15 baked in
// (R7: conflict-free; h reads are 8-lane broadcast = free).
// Sync protocol (R8/R9 lessons):
//  - tag travels WITH data (8B {ver,bits} relaxed agent atomics) — the only
//    ordering-free scheme; R9's done-word split raced (relaxed stores to
//    different lines reorder cross-XCD) and its sweep-retry became a storm.
//  - R8's regression source: 32K pollers on 128 shared msg-lines queue ahead
//    of the publishes at the coherence point (thundering herd).  Fix here:
//    NREP=8 replicated mailboxes; publishers store to all 8 (fire-and-forget,
//    off critical path), readers poll only region b&7 -> sharers/line /8.
// 2-slot ring per region, max skew 1 step, >= never needed (tag equality).
// ---------------------------------------------------------------------------
__device__ __forceinline__ float fsigmoid_(float x) {
    return 1.0f / (1.0f + __expf(-x));
}
__device__ __forceinline__ float ftanh_(float x) {
    x = fminf(fmaxf(x, -10.0f), 10.0f);
    const float e = __expf(2.0f * x);
    return (e - 1.0f) / (e + 1.0f);
}
__device__ __forceinline__ unsigned bf16rne_(float f) {   // finite inputs
    const unsigned u = __float_as_uint(f);
    return (u + 0x7FFFu + ((u >> 16) & 1u)) >> 16;
}
__device__ __forceinline__ float bf_lo_(unsigned u) {
    return __uint_as_float(u << 16);
}
__device__ __forceinline__ float bf_hi_(unsigned u) {
    return __uint_as_float(u & 0xFFFF0000u);
}

__global__ __launch_bounds__(NTHR, 1) void lstm_scan(
    const float* __restrict__ xg, const float* __restrict__ w_hh,
    const float* __restrict__ h0, const float* __restrict__ c0,
    unsigned long long* h_msg,           // [NREP][2][1024] {tag,bits}
    float* __restrict__ h_fin, float* __restrict__ c_fin)
{
    extern __shared__ char smem[];
    unsigned* w_lds   = (unsigned*)smem;            // 32768 u32 (64 rows bf16)
    float*    h_lds   = (float*)(smem + 131072);    // 1024 f32
    float*    xg_lds  = h_lds + H_DIM;              // 64
    float*    dot_lds = xg_lds + 64;                // 64

    const int tid  = threadIdx.x;
    const int b    = blockIdx.x;
    const int lane = tid & 63;
    const int wv   = tid >> 6;           // wave 0..7
    const int r    = tid >> 3;           // gate-row within block 0..63
    const int j    = tid & 7;            // k-slice (128 floats)
    const int g    = r >> 4;             // gate 0..3
    const int m    = r & 15;             // h-lane within block
    const int grow = g * 1024 + 16 * b + m;

    // ---- stage weights: fp32 global -> bf16 packed; slot i holds global
    // chunk c=(i+j)&15 (rotation baked into storage)
    {
        const float* wsrc = w_hh + (size_t)grow * 1024 + j * 128;
        uint4* wdst = (uint4*)w_lds + (size_t)wv * 1024 + lane;
        #pragma unroll
        for (int i = 0; i < 16; ++i) {
            const int c = (i + j) & 15;
            const float4 a = ((const float4*)(wsrc + c * 8))[0];
            const float4 d = ((const float4*)(wsrc + c * 8))[1];
            uint4 u;
            u.x = bf16rne_(a.x) | (bf16rne_(a.y) << 16);
            u.y = bf16rne_(a.z) | (bf16rne_(a.w) << 16);
            u.z = bf16rne_(d.x) | (bf16rne_(d.y) << 16);
            u.w = bf16rne_(d.z) | (bf16rne_(d.w) << 16);
            wdst[i * 64] = u;
        }
    }

    float c_reg = 0.0f;
    if (tid < 16) c_reg = c0[16 * b + tid];

    // h version 0 from h0
    ((float2*)h_lds)[tid] = ((const float2*)h0)[tid];

    // prefetch xg for t=0 (tid<64 owns (gate=tid>>4, lane m=tid&15))
    float xc = 0.0f;
    if (tid < 64)
        xc = xg[(size_t)(tid >> 4) * 1024 + 16 * b + (tid & 15)];
    __syncthreads();

    const uint4*  wrd = (const uint4*)w_lds + (size_t)wv * 1024 + lane;
    const float4* h4  = (const float4*)h_lds + j * 32;

    // prime the weight registers (reloaded each iter during the sync window)
    uint4 wreg[16];
    #pragma unroll
    for (int i = 0; i < 16; ++i) wreg[i] = wrd[i * 64];

    for (int t = 0; t < T_SEQ; ++t) {
        // stage this step's xg into LDS; issue next step's prefetch
        if (tid < 64) {
            xg_lds[tid] = xc;
            if (t < T_SEQ - 1)
                xc = xg[(size_t)(t + 1) * G4 + (tid >> 4) * 1024 + 16 * b + (tid & 15)];
        }

        // 128-MAC partial dot: bf16 weights (registers) x fp32 h (LDS bcast)
        float acc = 0.0f;
        #pragma unroll
        for (int i = 0; i < 16; ++i) {
            const int c = (i + j) & 15;
            const uint4  u  = wreg[i];
            const float4 ha = h4[2 * c];
            const float4 hb = h4[2 * c + 1];
            acc = fmaf(bf_lo_(u.x), ha.x, acc);
            acc = fmaf(bf_hi_(u.x), ha.y, acc);
            acc = fmaf(bf_lo_(u.y), ha.z, acc);
            acc = fmaf(bf_hi_(u.y), ha.w, acc);
            acc = fmaf(bf_lo_(u.z), hb.x, acc);
            acc = fmaf(bf_hi_(u.z), hb.y, acc);
            acc = fmaf(bf_lo_(u.w), hb.z, acc);
            acc = fmaf(bf_hi_(u.w), hb.w, acc);
        }
        acc += __shfl_xor(acc, 1);
        acc += __shfl_xor(acc, 2);
        acc += __shfl_xor(acc, 4);
        if (j == 0) dot_lds[r] = acc;
        __syncthreads();                                       // (A)

        // gate-parallel pointwise: 64 threads do one transcendental each,
        // 16 finalize via wave shuffles, then publish to all NREP mailboxes
        if (tid < 64) {
            const float x   = xg_lds[tid] + dot_lds[tid];
            const float act = ((tid >> 4) == 2) ? ftanh_(x) : fsigmoid_(x);
            const int   mm  = tid & 15;
            const float a_i = __shfl(act, mm, 64);
            const float a_f = __shfl(act, mm + 16, 64);
            const float a_g = __shfl(act, mm + 32, 64);
            const float a_o = __shfl(act, mm + 48, 64);
            if (tid < 16) {
                c_reg = a_f * c_reg + a_i * a_g;
                const float hn = a_o * ftanh_(c_reg);
                const unsigned long long msg =
                    ((unsigned long long)(unsigned)(t + 1) << 32) | __float_as_uint(hn);
                const size_t slot = (size_t)((t + 1) & 1) * H_DIM + 16 * b + tid;
                #pragma unroll
                for (int rr = 0; rr < NREP; ++rr)
                    __hip_atomic_store(&h_msg[(size_t)rr * 2 * H_DIM + slot],
                                       msg, __ATOMIC_RELAXED, __HIP_MEMORY_SCOPE_AGENT);
                if (t == T_SEQ - 1) {
                    h_fin[16 * b + tid] = hn;
                    c_fin[16 * b + tid] = c_reg;
                }
            }
        }

        // re-issue weight loads for next iteration; latency hides under sync
        #pragma unroll
        for (int i = 0; i < 16; ++i) wreg[i] = wrd[i * 64];

        // gather h version t+1 from OUR replica region only (sharers/line /8)
        if (t < T_SEQ - 1) {
            const unsigned ver = (unsigned)(t + 1);
            const unsigned long long* src =
                h_msg + (size_t)(b & (NREP - 1)) * 2 * H_DIM
                      + (size_t)(ver & 1) * H_DIM + 2 * tid;
            unsigned long long v0, v1;
            for (;;) {
                v0 = __hip_atomic_load(src + 0, __ATOMIC_RELAXED, __HIP_MEMORY_SCOPE_AGENT);
                v1 = __hip_atomic_load(src + 1, __ATOMIC_RELAXED, __HIP_MEMORY_SCOPE_AGENT);
                if (((unsigned)(v0 >> 32) == ver) & ((unsigned)(v1 >> 32) == ver))
                    break;
                __builtin_amdgcn_s_sleep(1);
            }
            float2 hv;
            hv.x = __uint_as_float((unsigned)v0);
            hv.y = __uint_as_float((unsigned)v1);
            ((float2*)h_lds)[tid] = hv;
            __syncthreads();                                   // (C)
        }
    }
}

// ---------------------------------------------------------------------------
// K3: four 256x1024 mat-vec projections + bias.  One output per 32-lane group.
// ---------------------------------------------------------------------------
__global__ __launch_bounds__(256) void proj_kernel(
    const float* __restrict__ h_fin, const float* __restrict__ c_fin,
    const float* __restrict__ W_hm, const float* __restrict__ b_hm,
    const float* __restrict__ W_hv, const float* __restrict__ b_hv,
    const float* __restrict__ W_cm, const float* __restrict__ b_cm,
    const float* __restrict__ W_cv, const float* __restrict__ b_cv,
    float* __restrict__ out)
{
    const int tid = threadIdx.x;
    const int g32 = tid >> 5;
    const int j   = tid & 31;
    const int o   = blockIdx.x * 8 + g32;   // 0..1023
    const int mat = o >> 8;
    const int l   = o & 255;

    const float* W;  const float* bias;  const float* vec;
    if      (mat == 0) { W = W_hm; bias = b_hm; vec = h_fin; }
    else if (mat == 1) { W = W_hv; bias = b_hv; vec = h_fin; }
    else if (mat == 2) { W = W_cm; bias = b_cm; vec = c_fin; }
    else               { W = W_cv; bias = b_cv; vec = c_fin; }

    const float* wrow = W + (size_t)l * 1024;
    float acc = 0.0f;
    #pragma unroll
    for (int i = 0; i < 8; ++i) {
        const float4 wv = *(const float4*)(wrow + i * 128 + j * 4);
        const float4 xv = *(const float4*)(vec  + i * 128 + j * 4);
        acc += wv.x * xv.x + wv.y * xv.y + wv.z * xv.z + wv.w * xv.w;
    }
    acc += __shfl_xor(acc, 1);
    acc += __shfl_xor(acc, 2);
    acc += __shfl_xor(acc, 4);
    acc += __shfl_xor(acc, 8);
    acc += __shfl_xor(acc, 16);
    if (j == 0) out[o] = acc + bias[l];
}

// ---------------------------------------------------------------------------
extern "C" void kernel_launch(void* const* d_in, const int* in_sizes, int n_in,
                              void* d_out, int out_size, void* d_ws, size_t ws_size,
                              hipStream_t stream)
{
    const int*   tokens = (const int*)  d_in[0];
    const float* h0     = (const float*)d_in[1];
    const float* c0     = (const float*)d_in[2];
    const float* emb    = (const float*)d_in[3];
    const float* w_ih   = (const float*)d_in[4];
    const float* w_hh   = (const float*)d_in[5];
    const float* b_ih   = (const float*)d_in[6];
    const float* b_hh   = (const float*)d_in[7];
    const float* W_hm   = (const float*)d_in[8];
    const float* b_hm   = (const float*)d_in[9];
    const float* W_hv   = (const float*)d_in[10];
    const float* b_hv   = (const float*)d_in[11];
    const float* W_cm   = (const float*)d_in[12];
    const float* b_cm   = (const float*)d_in[13];
    const float* W_cv   = (const float*)d_in[14];
    const float* b_cv   = (const float*)d_in[15];
    float* out = (float*)d_out;

    char* ws = (char*)d_ws;
    float*              xg    = (float*)ws;            // T*4H fp32 = 64 MB
    size_t              off   = (size_t)T_SEQ * G4 * sizeof(float);
    unsigned long long* h_msg = (unsigned long long*)(ws + off);
    off += (size_t)NREP * 2 * H_DIM * sizeof(unsigned long long);   // 128 KB
    float* h_fin = (float*)(ws + off); off += H_DIM * sizeof(float);
    float* c_fin = (float*)(ws + off); off += H_DIM * sizeof(float);

    // allow 132.6 KB dynamic LDS for the scan kernel (host attr, capture-safe)
    hipFuncSetAttribute((const void*)lstm_scan,
                        hipFuncAttributeMaxDynamicSharedMemorySize,
                        SCAN_LDS_BYTES);

    // clear stale tags in all replica regions (part of the captured graph)
    hipMemsetAsync(h_msg, 0xFF,
                   (size_t)NREP * 2 * H_DIM * sizeof(unsigned long long), stream);

    xg_gemm<<<dim3(32, 32), 256, 0, stream>>>(tokens, emb, w_ih, b_ih, b_hh, xg);
    lstm_scan<<<NBLK, NTHR, SCAN_LDS_BYTES, stream>>>(xg, w_hh, h0, c0, h_msg,
                                                      h_fin, c_fin);
    proj_kernel<<<128, 256, 0, stream>>>(h_fin, c_fin, W_hm, b_hm, W_hv, b_hv,
                                         W_cm, b_cm, W_cv, b_cv, out);
}

// Round 12
// 8025.596 us; speedup vs baseline: 1.5540x; 1.1773x over previous
//
#include <hip/hip_runtime.h>
#include <math.h>

#define T_SEQ 4096
#define H_DIM 1024
#define G4    4096
#define NBLK  64      // scan blocks; each owns 16 h-lanes (64 gate rows)
#define NTHR  512
// dynamic LDS: 128KB f16 weights + 2KB f16 h + 4KB dot_part[2][8][64]
#define SCAN_LDS_BYTES (131072 + 2048 + 4096)

// NOTE: __builtin_amdgcn_cvt_pkrtz / fdot2 use the __fp16 vector type
// (clang builtin sig "fV2hV2hfb"); _Float16 vectors are incompatible (R11).
typedef __fp16 half2_t __attribute__((ext_vector_type(2)));
union U32H2 { unsigned u; half2_t h; };
__device__ __forceinline__ half2_t as_h2(unsigned u) { U32H2 c; c.u = u; return c.h; }
__device__ __forceinline__ unsigned pkh2(float a, float b) {
    U32H2 c; c.h = __builtin_amdgcn_cvt_pkrtz(a, b); return c.u;
}

// ---------------------------------------------------------------------------
// K1: xg[t][j] = dot(embedding[tokens[t]], w_ih[j]) + b_ih[j] + b_hh[j]
// fp32 GEMM, 128x128 tile, BK=16, 256 threads, 8x8 microtile.
// ---------------------------------------------------------------------------
__global__ __launch_bounds__(256) void xg_gemm(
    const int* __restrict__ tokens, const float* __restrict__ emb,
    const float* __restrict__ w_ih, const float* __restrict__ b_ih,
    const float* __restrict__ b_hh, float* __restrict__ xg)
{
    __shared__ float As[16][128];
    __shared__ float Bs[16][128];
    __shared__ int   tk[128];

    const int tid  = threadIdx.x;
    const int row0 = blockIdx.y * 128;
    const int col0 = blockIdx.x * 128;

    if (tid < 128) tk[tid] = tokens[row0 + tid];
    __syncthreads();

    const int r    = tid >> 1;
    const int half = tid & 1;
    const int tx   = tid & 15;
    const int ty   = tid >> 4;

    const float* ap_base = emb + (size_t)tk[r] * 1024 + half * 8;
    const float* bp_base = w_ih + (size_t)(col0 + r) * 1024 + half * 8;

    float acc[8][8] = {};

    for (int kc = 0; kc < 1024; kc += 16) {
        const float4 a0 = ((const float4*)(ap_base + kc))[0];
        const float4 a1 = ((const float4*)(ap_base + kc))[1];
        const float4 b0 = ((const float4*)(bp_base + kc))[0];
        const float4 b1 = ((const float4*)(bp_base + kc))[1];
        __syncthreads();
        const int kb = half * 8;
        As[kb+0][r] = a0.x; As[kb+1][r] = a0.y; As[kb+2][r] = a0.z; As[kb+3][r] = a0.w;
        As[kb+4][r] = a1.x; As[kb+5][r] = a1.y; As[kb+6][r] = a1.z; As[kb+7][r] = a1.w;
        Bs[kb+0][r] = b0.x; Bs[kb+1][r] = b0.y; Bs[kb+2][r] = b0.z; Bs[kb+3][r] = b0.w;
        Bs[kb+4][r] = b1.x; Bs[kb+5][r] = b1.y; Bs[kb+6][r] = b1.z; Bs[kb+7][r] = b1.w;
        __syncthreads();
        #pragma unroll
        for (int k = 0; k < 16; ++k) {
            const float4 a0v = *(const float4*)&As[k][ty*8];
            const float4 a1v = *(const float4*)&As[k][ty*8+4];
            const float4 b0v = *(const float4*)&Bs[k][tx*8];
            const float4 b1v = *(const float4*)&Bs[k][tx*8+4];
            const float aa[8] = {a0v.x,a0v.y,a0v.z,a0v.w,a1v.x,a1v.y,a1v.z,a1v.w};
            const float bb[8] = {b0v.x,b0v.y,b0v.z,b0v.w,b1v.x,b1v.y,b1v.z,b1v.w};
            #pragma unroll
            for (int ii = 0; ii < 8; ++ii)
                #pragma unroll
                for (int jj = 0; jj < 8; ++jj)
                    acc[ii][jj] = fmaf(aa[ii], bb[jj], acc[ii][jj]);
        }
    }

    const int ccol = col0 + tx * 8;
    float bs[8];
    #pragma unroll
    for (int jj = 0; jj < 8; ++jj) bs[jj] = b_ih[ccol + jj] + b_hh[ccol + jj];
    #pragma unroll
    for (int ii = 0; ii < 8; ++ii) {
        float* orow = xg + (size_t)(row0 + ty*8 + ii) * G4 + ccol;
        float4 o0, o1;
        o0.x = acc[ii][0] + bs[0]; o0.y = acc[ii][1] + bs[1];
        o0.z = acc[ii][2] + bs[2]; o0.w = acc[ii][3] + bs[3];
        o1.x = acc[ii][4] + bs[4]; o1.y = acc[ii][5] + bs[5];
        o1.z = acc[ii][6] + bs[6]; o1.w = acc[ii][7] + bs[7];
        ((float4*)orow)[0] = o0;
        ((float4*)orow)[1] = o1;
    }
}

// ---------------------------------------------------------------------------
// K2: persistent LSTM scan, wave-sliced.  64 blocks x 512 threads; block b
// owns h-lanes {16b..16b+15} (64 gate rows).  Wave w owns h-chunk
// [128w,128w+128): it polls/gathers/stores that chunk and computes every
// row's partial dot against it (h reads = pure wave-broadcast, no rotation
// needed).  Weights + h in f16 LDS; dot via v_dot2_f32_f16 (2 MAC/op).
// Sync (R8-R10 lessons): all agent atomics serialize at the die-level
// coherence point — total poll RATE is what matters.  Sentinel-gated detect:
// publisher's 16 msgs come from ONE wave-store instruction; each consumer
// wave polls just 8 sentinels (lanes 0-7, one per publisher), then does one
// tag-verified 2-msg/lane gather (micro-retry covers completion skew).
// Poll rate drops 16x vs R8.  Tag travels with data; no fences anywhere.
// dot_part double-buffered by t&1 so waves free-run into the next poll while
// wave 0 finishes the pointwise (safety: block publishing t+2 implies all
// blocks consumed t+1 — full-coverage lattice).
// ---------------------------------------------------------------------------
__device__ __forceinline__ float fsigmoid_(float x) {
    return 1.0f / (1.0f + __expf(-x));
}
__device__ __forceinline__ float ftanh_(float x) {
    x = fminf(fmaxf(x, -10.0f), 10.0f);
    const float e = __expf(2.0f * x);
    return (e - 1.0f) / (e + 1.0f);
}

__global__ __launch_bounds__(NTHR, 1) void lstm_scan(
    const float* __restrict__ xg, const float* __restrict__ w_hh,
    const float* __restrict__ h0, const float* __restrict__ c0,
    unsigned long long* h_msg,           // [2][1024] {tag,fp32 bits}
    float* __restrict__ h_fin, float* __restrict__ c_fin)
{
    extern __shared__ char smem[];
    unsigned* w_lds = (unsigned*)smem;                    // 32768 u32 (f16 pairs)
    unsigned* hbuf  = (unsigned*)(smem + 131072);         // 512 u32 (1024 f16)
    float*    dpart = (float*)(smem + 131072 + 2048);     // [2][8][64]

    const int tid  = threadIdx.x;
    const int b    = blockIdx.x;
    const int wv   = tid >> 6;           // wave 0..7 = h-chunk index
    const int lane = tid & 63;           // row within block (gate g=lane>>4, m=lane&15)

    // ---- stage weights fp32 -> f16, layout [wv][i][lane] uint4 (lane-consec)
    {
        const int grow = (lane >> 4) * 1024 + 16 * b + (lane & 15);
        const float* wsrc = w_hh + (size_t)grow * 1024 + wv * 128;
        uint4* wdst = (uint4*)w_lds + wv * 1024 + lane;
        #pragma unroll
        for (int i = 0; i < 16; ++i) {
            const float4 a = ((const float4*)wsrc)[2 * i];
            const float4 d = ((const float4*)wsrc)[2 * i + 1];
            uint4 u;
            u.x = pkh2(a.x, a.y); u.y = pkh2(a.z, a.w);
            u.z = pkh2(d.x, d.y); u.w = pkh2(d.z, d.w);
            wdst[i * 64] = u;
        }
    }

    float c_reg = 0.0f;
    if (tid < 16) c_reg = c0[16 * b + tid];
    float xc = 0.0f;
    if (tid < 64) xc = xg[(size_t)(tid >> 4) * 1024 + 16 * b + (tid & 15)];

    // stage h0 chunk (lane owns h values 128wv+2lane, +1)
    {
        const float2 hh = ((const float2*)h0)[wv * 64 + lane];
        hbuf[wv * 64 + lane] = pkh2(hh.x, hh.y);
    }
    __syncthreads();

    const uint4* wrd = (const uint4*)w_lds + wv * 1024 + lane;
    const uint4* h4  = (const uint4*)hbuf + wv * 16;     // chunk = 16 uint4, broadcast

    uint4 wreg[16];
    #pragma unroll
    for (int i = 0; i < 16; ++i) wreg[i] = wrd[i * 64];

    for (int t = 0; t < T_SEQ; ++t) {
        if (t > 0) {
            const unsigned ver = (unsigned)t;
            const unsigned long long* base = h_msg + (size_t)(t & 1) * H_DIM;

            // sentinel detect: lanes 0..7 watch publisher (8wv+lane)'s first msg
            {
                const unsigned long long* s = base + 128 * wv + 16 * lane;
                for (;;) {
                    unsigned tg = ver;
                    if (lane < 8)
                        tg = (unsigned)(__hip_atomic_load(s, __ATOMIC_RELAXED,
                                                          __HIP_MEMORY_SCOPE_AGENT) >> 32);
                    if (__all(tg == ver)) break;
                    __builtin_amdgcn_s_sleep(1);
                }
            }
            // gather own 2 msgs (tag-verified; retry covers completion skew)
            const unsigned long long* src = base + 128 * wv + 2 * lane;
            unsigned long long v0, v1;
            for (;;) {
                v0 = __hip_atomic_load(src + 0, __ATOMIC_RELAXED, __HIP_MEMORY_SCOPE_AGENT);
                v1 = __hip_atomic_load(src + 1, __ATOMIC_RELAXED, __HIP_MEMORY_SCOPE_AGENT);
                if (((unsigned)(v0 >> 32) == ver) & ((unsigned)(v1 >> 32) == ver))
                    break;
            }
            hbuf[wv * 64 + lane] = pkh2(__uint_as_float((unsigned)v0),
                                        __uint_as_float((unsigned)v1));
        }
        // drain LDS writes; same-wave lockstep makes them visible to all lanes
        asm volatile("s_waitcnt lgkmcnt(0)" ::: "memory");
        __builtin_amdgcn_wave_barrier();
        __builtin_amdgcn_sched_barrier(0);

        // 128-MAC partial dot: f16 weights (regs) x f16 h chunk (LDS broadcast)
        float acc = 0.0f;
        #pragma unroll
        for (int i = 0; i < 16; ++i) {
            const uint4 uw = wreg[i];
            const uint4 uh = h4[i];
            acc = __builtin_amdgcn_fdot2(as_h2(uw.x), as_h2(uh.x), acc, false);
            acc = __builtin_amdgcn_fdot2(as_h2(uw.y), as_h2(uh.y), acc, false);
            acc = __builtin_amdgcn_fdot2(as_h2(uw.z), as_h2(uh.z), acc, false);
            acc = __builtin_amdgcn_fdot2(as_h2(uw.w), as_h2(uh.w), acc, false);
        }
        dpart[(t & 1) * 512 + wv * 64 + lane] = acc;

        // reload wreg for next iter (latency hides under barrier+pointwise)
        #pragma unroll
        for (int i = 0; i < 16; ++i) wreg[i] = wrd[i * 64];

        // prefetch next xg (consumed next iteration's pointwise)
        float xn = 0.0f;
        if ((tid < 64) & (t < T_SEQ - 1))
            xn = xg[(size_t)(t + 1) * G4 + (tid >> 4) * 1024 + 16 * b + (tid & 15)];

        __syncthreads();

        // gate-parallel pointwise + publish (wave 0); other waves free-run
        // into the next poll (dpart double-buffer makes this safe)
        if (tid < 64) {
            const float* dp = dpart + (t & 1) * 512;
            float x = xc;
            #pragma unroll
            for (int w8 = 0; w8 < 8; ++w8) x += dp[w8 * 64 + tid];
            const float act = ((tid >> 4) == 2) ? ftanh_(x) : fsigmoid_(x);
            const int m = tid & 15;
            const float a_i = __shfl(act, m, 64);
            const float a_f = __shfl(act, m + 16, 64);
            const float a_g = __shfl(act, m + 32, 64);
            const float a_o = __shfl(act, m + 48, 64);
            if (tid < 16) {
                c_reg = a_f * c_reg + a_i * a_g;
                const float hn = a_o * ftanh_(c_reg);
                if (t < T_SEQ - 1) {
                    const unsigned long long msg =
                        ((unsigned long long)(unsigned)(t + 1) << 32) | __float_as_uint(hn);
                    __hip_atomic_store(&h_msg[(size_t)((t + 1) & 1) * H_DIM + 16 * b + tid],
                                       msg, __ATOMIC_RELAXED, __HIP_MEMORY_SCOPE_AGENT);
                } else {
                    h_fin[16 * b + tid] = hn;
                    c_fin[16 * b + tid] = c_reg;
                }
            }
        }
        xc = xn;
    }
}

// ---------------------------------------------------------------------------
// K3: four 256x1024 mat-vec projections + bias.  One output per 32-lane group.
// ---------------------------------------------------------------------------
__global__ __launch_bounds__(256) void proj_kernel(
    const float* __restrict__ h_fin, const float* __restrict__ c_fin,
    const float* __restrict__ W_hm, const float* __restrict__ b_hm,
    const float* __restrict__ W_hv, const float* __restrict__ b_hv,
    const float* __restrict__ W_cm, const float* __restrict__ b_cm,
    const float* __restrict__ W_cv, const float* __restrict__ b_cv,
    float* __restrict__ out)
{
    const int tid = threadIdx.x;
    const int g32 = tid >> 5;
    const int j   = tid & 31;
    const int o   = blockIdx.x * 8 + g32;   // 0..1023
    const int mat = o >> 8;
    const int l   = o & 255;

    const float* W;  const float* bias;  const float* vec;
    if      (mat == 0) { W = W_hm; bias = b_hm; vec = h_fin; }
    else if (mat == 1) { W = W_hv; bias = b_hv; vec = h_fin; }
    else if (mat == 2) { W = W_cm; bias = b_cm; vec = c_fin; }
    else               { W = W_cv; bias = b_cv; vec = c_fin; }

    const float* wrow = W + (size_t)l * 1024;
    float acc = 0.0f;
    #pragma unroll
    for (int i = 0; i < 8; ++i) {
        const float4 wv = *(const float4*)(wrow + i * 128 + j * 4);
        const float4 xv = *(const float4*)(vec  + i * 128 + j * 4);
        acc += wv.x * xv.x + wv.y * xv.y + wv.z * xv.z + wv.w * xv.w;
    }
    acc += __shfl_xor(acc, 1);
    acc += __shfl_xor(acc, 2);
    acc += __shfl_xor(acc, 4);
    acc += __shfl_xor(acc, 8);
    acc += __shfl_xor(acc, 16);
    if (j == 0) out[o] = acc + bias[l];
}

// ---------------------------------------------------------------------------
extern "C" void kernel_launch(void* const* d_in, const int* in_sizes, int n_in,
                              void* d_out, int out_size, void* d_ws, size_t ws_size,
                              hipStream_t stream)
{
    const int*   tokens = (const int*)  d_in[0];
    const float* h0     = (const float*)d_in[1];
    const float* c0     = (const float*)d_in[2];
    const float* emb    = (const float*)d_in[3];
    const float* w_ih   = (const float*)d_in[4];
    const float* w_hh   = (const float*)d_in[5];
    const float* b_ih   = (const float*)d_in[6];
    const float* b_hh   = (const float*)d_in[7];
    const float* W_hm   = (const float*)d_in[8];
    const float* b_hm   = (const float*)d_in[9];
    const float* W_hv   = (const float*)d_in[10];
    const float* b_hv   = (const float*)d_in[11];
    const float* W_cm   = (const float*)d_in[12];
    const float* b_cm   = (const float*)d_in[13];
    const float* W_cv   = (const float*)d_in[14];
    const float* b_cv   = (const float*)d_in[15];
    float* out = (float*)d_out;

    char* ws = (char*)d_ws;
    float*              xg    = (float*)ws;            // T*4H fp32 = 64 MB
    size_t              off   = (size_t)T_SEQ * G4 * sizeof(float);
    unsigned long long* h_msg = (unsigned long long*)(ws + off);
    off += 2 * H_DIM * sizeof(unsigned long long);     // 16 KB
    float* h_fin = (float*)(ws + off); off += H_DIM * sizeof(float);
    float* c_fin = (float*)(ws + off); off += H_DIM * sizeof(float);

    // allow 134 KB dynamic LDS for the scan kernel (host attr, capture-safe)
    (void)hipFuncSetAttribute((const void*)lstm_scan,
                              hipFuncAttributeMaxDynamicSharedMemorySize,
                              SCAN_LDS_BYTES);

    // clear stale tags (part of the captured graph => replay-safe)
    hipMemsetAsync(h_msg, 0xFF, 2 * H_DIM * sizeof(unsigned long long), stream);

    xg_gemm<<<dim3(32, 32), 256, 0, stream>>>(tokens, emb, w_ih, b_ih, b_hh, xg);
    lstm_scan<<<NBLK, NTHR, SCAN_LDS_BYTES, stream>>>(xg, w_hh, h0, c0, h_msg,
                                                      h_fin, c_fin);
    proj_kernel<<<128, 256, 0, stream>>>(h_fin, c_fin, W_hm, b_hm, W_hv, b_hv,
                                         W_cm, b_cm, W_cv, b_cv, out);
}

// Round 13
// 7241.794 us; speedup vs baseline: 1.7222x; 1.1082x over previous
//
#include <hip/hip_runtime.h>
#include <math.h>

#define T_SEQ 4096
#define H_DIM 1024
#define G4    4096
#define NBLK  64      // scan blocks; each owns 16 h-lanes (64 gate rows)
#define NTHR  512
// dynamic LDS: 128KB f16 weights + 2KB f16 h + 4KB dot_part[2][8][64]
#define SCAN_LDS_BYTES (131072 + 2048 + 4096)

// __builtin_amdgcn_cvt_pkrtz / fdot2 use the __fp16 vector type (R11 lesson).
typedef __fp16 half2_t __attribute__((ext_vector_type(2)));
union U32H2 { unsigned u; half2_t h; };
__device__ __forceinline__ half2_t as_h2(unsigned u) { U32H2 c; c.u = u; return c.h; }
__device__ __forceinline__ unsigned pkh2(float a, float b) {
    U32H2 c; c.h = __builtin_amdgcn_cvt_pkrtz(a, b); return c.u;
}

// ---------------------------------------------------------------------------
// K1: xg[t][j] = dot(embedding[tokens[t]], w_ih[j]) + b_ih[j] + b_hh[j]
// f16 GEMM via v_dot2_f32_f16: 128x128 tile, BK=16, 256 threads, 8x8
// microtile.  Staging converts fp32->f16 pairs (k-pairs packed in u32).
// ---------------------------------------------------------------------------
__global__ __launch_bounds__(256) void xg_gemm(
    const int* __restrict__ tokens, const float* __restrict__ emb,
    const float* __restrict__ w_ih, const float* __restrict__ b_ih,
    const float* __restrict__ b_hh, float* __restrict__ xg)
{
    __shared__ unsigned As2[8][128];   // [k-pair][row] f16x2
    __shared__ unsigned Bs2[8][128];
    __shared__ int      tk[128];

    const int tid  = threadIdx.x;
    const int row0 = blockIdx.y * 128;
    const int col0 = blockIdx.x * 128;

    if (tid < 128) tk[tid] = tokens[row0 + tid];
    __syncthreads();

    const int r    = tid >> 1;      // staging row 0..127
    const int half = tid & 1;       // staging k-half (8 floats each)
    const int tx   = tid & 15;
    const int ty   = tid >> 4;

    const float* ap_base = emb + (size_t)tk[r] * 1024 + half * 8;
    const float* bp_base = w_ih + (size_t)(col0 + r) * 1024 + half * 8;

    float acc[8][8] = {};

    for (int kc = 0; kc < 1024; kc += 16) {
        const float4 a0 = ((const float4*)(ap_base + kc))[0];
        const float4 a1 = ((const float4*)(ap_base + kc))[1];
        const float4 b0 = ((const float4*)(bp_base + kc))[0];
        const float4 b1 = ((const float4*)(bp_base + kc))[1];
        __syncthreads();   // previous compute finished before overwrite
        const int kb = half * 4;
        As2[kb+0][r] = pkh2(a0.x, a0.y);
        As2[kb+1][r] = pkh2(a0.z, a0.w);
        As2[kb+2][r] = pkh2(a1.x, a1.y);
        As2[kb+3][r] = pkh2(a1.z, a1.w);
        Bs2[kb+0][r] = pkh2(b0.x, b0.y);
        Bs2[kb+1][r] = pkh2(b0.z, b0.w);
        Bs2[kb+2][r] = pkh2(b1.x, b1.y);
        Bs2[kb+3][r] = pkh2(b1.z, b1.w);
        __syncthreads();
        #pragma unroll
        for (int kk = 0; kk < 8; ++kk) {
            unsigned aa[8], bb[8];
            #pragma unroll
            for (int ii = 0; ii < 8; ++ii) aa[ii] = As2[kk][ty*8 + ii];
            #pragma unroll
            for (int jj = 0; jj < 8; ++jj) bb[jj] = Bs2[kk][tx*8 + jj];
            #pragma unroll
            for (int ii = 0; ii < 8; ++ii)
                #pragma unroll
                for (int jj = 0; jj < 8; ++jj)
                    acc[ii][jj] = __builtin_amdgcn_fdot2(
                        as_h2(aa[ii]), as_h2(bb[jj]), acc[ii][jj], false);
        }
    }

    const int ccol = col0 + tx * 8;
    float bs[8];
    #pragma unroll
    for (int jj = 0; jj < 8; ++jj) bs[jj] = b_ih[ccol + jj] + b_hh[ccol + jj];
    #pragma unroll
    for (int ii = 0; ii < 8; ++ii) {
        float* orow = xg + (size_t)(row0 + ty*8 + ii) * G4 + ccol;
        float4 o0, o1;
        o0.x = acc[ii][0] + bs[0]; o0.y = acc[ii][1] + bs[1];
        o0.z = acc[ii][2] + bs[2]; o0.w = acc[ii][3] + bs[3];
        o1.x = acc[ii][4] + bs[4]; o1.y = acc[ii][5] + bs[5];
        o1.z = acc[ii][6] + bs[6]; o1.w = acc[ii][7] + bs[7];
        ((float4*)orow)[0] = o0;
        ((float4*)orow)[1] = o1;
    }
}

// ---------------------------------------------------------------------------
// K2: persistent LSTM scan, wave-sliced.  64 blocks x 512 threads; block b
// owns h-lanes {16b..16b+15} (64 gate rows).  Wave w owns h-chunk
// [128w,128w+128): polls/gathers/stores that chunk, computes every row's
// partial dot against it.  Weights + h in f16 LDS; dot via v_dot2_f32_f16.
// Sync model (R5/R8/R10/R12 synthesis): exchange cost ~1.2-1.5us/step is
// INTRINSIC (publish->coherence-point visibility + cross-XCD gather); poll
// rate and replication don't move it at 64 participants.  So: MERGED
// detect+gather — each lane directly tag-polls its own 2 msgs (one serial
// hop instead of R12's sentinel+gather two hops).  Tag travels with data;
// no fences.  2-slot ring, max skew 1 step (publish-precedes-poll lattice).
// dpart double-buffered so waves free-run into the next poll.
// ---------------------------------------------------------------------------
__device__ __forceinline__ float fsigmoid_(float x) {
    return 1.0f / (1.0f + __expf(-x));
}
__device__ __forceinline__ float ftanh_(float x) {
    x = fminf(fmaxf(x, -10.0f), 10.0f);
    const float e = __expf(2.0f * x);
    return (e - 1.0f) / (e + 1.0f);
}

__global__ __launch_bounds__(NTHR, 1) void lstm_scan(
    const float* __restrict__ xg, const float* __restrict__ w_hh,
    const float* __restrict__ h0, const float* __restrict__ c0,
    unsigned long long* h_msg,           // [2][1024] {tag,fp32 bits}
    float* __restrict__ h_fin, float* __restrict__ c_fin)
{
    extern __shared__ char smem[];
    unsigned* w_lds = (unsigned*)smem;                    // 32768 u32 (f16 pairs)
    unsigned* hbuf  = (unsigned*)(smem + 131072);         // 512 u32 (1024 f16)
    float*    dpart = (float*)(smem + 131072 + 2048);     // [2][8][64]

    const int tid  = threadIdx.x;
    const int b    = blockIdx.x;
    const int wv   = tid >> 6;           // wave 0..7 = h-chunk index
    const int lane = tid & 63;           // row within block (gate g=lane>>4, m=lane&15)

    // ---- stage weights fp32 -> f16, layout [wv][i][lane] uint4 (lane-consec)
    {
        const int grow = (lane >> 4) * 1024 + 16 * b + (lane & 15);
        const float* wsrc = w_hh + (size_t)grow * 1024 + wv * 128;
        uint4* wdst = (uint4*)w_lds + wv * 1024 + lane;
        #pragma unroll
        for (int i = 0; i < 16; ++i) {
            const float4 a = ((const float4*)wsrc)[2 * i];
            const float4 d = ((const float4*)wsrc)[2 * i + 1];
            uint4 u;
            u.x = pkh2(a.x, a.y); u.y = pkh2(a.z, a.w);
            u.z = pkh2(d.x, d.y); u.w = pkh2(d.z, d.w);
            wdst[i * 64] = u;
        }
    }

    float c_reg = 0.0f;
    if (tid < 16) c_reg = c0[16 * b + tid];
    float xc = 0.0f;
    if (tid < 64) xc = xg[(size_t)(tid >> 4) * 1024 + 16 * b + (tid & 15)];

    // stage h0 chunk (lane owns h values 128wv+2lane, +1)
    {
        const float2 hh = ((const float2*)h0)[wv * 64 + lane];
        hbuf[wv * 64 + lane] = pkh2(hh.x, hh.y);
    }
    __syncthreads();

    const uint4* wrd = (const uint4*)w_lds + wv * 1024 + lane;
    const uint4* h4  = (const uint4*)hbuf + wv * 16;     // chunk = 16 uint4, broadcast

    uint4 wreg[16];
    #pragma unroll
    for (int i = 0; i < 16; ++i) wreg[i] = wrd[i * 64];

    for (int t = 0; t < T_SEQ; ++t) {
        if (t > 0) {
            // merged detect+gather: lane tag-polls its OWN two msgs directly
            const unsigned ver = (unsigned)t;
            const unsigned long long* src =
                h_msg + (size_t)(t & 1) * H_DIM + 128 * wv + 2 * lane;
            unsigned long long v0, v1;
            for (;;) {
                v0 = __hip_atomic_load(src + 0, __ATOMIC_RELAXED, __HIP_MEMORY_SCOPE_AGENT);
                v1 = __hip_atomic_load(src + 1, __ATOMIC_RELAXED, __HIP_MEMORY_SCOPE_AGENT);
                if (((unsigned)(v0 >> 32) == ver) & ((unsigned)(v1 >> 32) == ver))
                    break;
            }
            hbuf[wv * 64 + lane] = pkh2(__uint_as_float((unsigned)v0),
                                        __uint_as_float((unsigned)v1));
        }
        // drain LDS writes; same-wave lockstep makes them visible to all lanes
        asm volatile("s_waitcnt lgkmcnt(0)" ::: "memory");
        __builtin_amdgcn_wave_barrier();
        __builtin_amdgcn_sched_barrier(0);

        // 128-MAC partial dot: f16 weights (regs) x f16 h chunk (LDS broadcast)
        float acc = 0.0f;
        #pragma unroll
        for (int i = 0; i < 16; ++i) {
            const uint4 uw = wreg[i];
            const uint4 uh = h4[i];
            acc = __builtin_amdgcn_fdot2(as_h2(uw.x), as_h2(uh.x), acc, false);
            acc = __builtin_amdgcn_fdot2(as_h2(uw.y), as_h2(uh.y), acc, false);
            acc = __builtin_amdgcn_fdot2(as_h2(uw.z), as_h2(uh.z), acc, false);
            acc = __builtin_amdgcn_fdot2(as_h2(uw.w), as_h2(uh.w), acc, false);
        }
        dpart[(t & 1) * 512 + wv * 64 + lane] = acc;

        // reload wreg for next iter (latency hides under barrier+pointwise)
        #pragma unroll
        for (int i = 0; i < 16; ++i) wreg[i] = wrd[i * 64];

        // prefetch next xg (consumed next iteration's pointwise)
        float xn = 0.0f;
        if ((tid < 64) & (t < T_SEQ - 1))
            xn = xg[(size_t)(t + 1) * G4 + (tid >> 4) * 1024 + 16 * b + (tid & 15)];

        __syncthreads();

        // gate-parallel pointwise + publish (wave 0); other waves free-run
        // into the next poll (dpart double-buffer makes this safe)
        if (tid < 64) {
            const float* dp = dpart + (t & 1) * 512;
            float x = xc;
            #pragma unroll
            for (int w8 = 0; w8 < 8; ++w8) x += dp[w8 * 64 + tid];
            const float act = ((tid >> 4) == 2) ? ftanh_(x) : fsigmoid_(x);
            const int m = tid & 15;
            const float a_i = __shfl(act, m, 64);
            const float a_f = __shfl(act, m + 16, 64);
            const float a_g = __shfl(act, m + 32, 64);
            const float a_o = __shfl(act, m + 48, 64);
            if (tid < 16) {
                c_reg = a_f * c_reg + a_i * a_g;
                const float hn = a_o * ftanh_(c_reg);
                if (t < T_SEQ - 1) {
                    const unsigned long long msg =
                        ((unsigned long long)(unsigned)(t + 1) << 32) | __float_as_uint(hn);
                    __hip_atomic_store(&h_msg[(size_t)((t + 1) & 1) * H_DIM + 16 * b + tid],
                                       msg, __ATOMIC_RELAXED, __HIP_MEMORY_SCOPE_AGENT);
                } else {
                    h_fin[16 * b + tid] = hn;
                    c_fin[16 * b + tid] = c_reg;
                }
            }
        }
        xc = xn;
    }
}

// ---------------------------------------------------------------------------
// K3: four 256x1024 mat-vec projections + bias.  One output per 32-lane group.
// ---------------------------------------------------------------------------
__global__ __launch_bounds__(256) void proj_kernel(
    const float* __restrict__ h_fin, const float* __restrict__ c_fin,
    const float* __restrict__ W_hm, const float* __restrict__ b_hm,
    const float* __restrict__ W_hv, const float* __restrict__ b_hv,
    const float* __restrict__ W_cm, const float* __restrict__ b_cm,
    const float* __restrict__ W_cv, const float* __restrict__ b_cv,
    float* __restrict__ out)
{
    const int tid = threadIdx.x;
    const int g32 = tid >> 5;
    const int j   = tid & 31;
    const int o   = blockIdx.x * 8 + g32;   // 0..1023
    const int mat = o >> 8;
    const int l   = o & 255;

    const float* W;  const float* bias;  const float* vec;
    if      (mat == 0) { W = W_hm; bias = b_hm; vec = h_fin; }
    else if (mat == 1) { W = W_hv; bias = b_hv; vec = h_fin; }
    else if (mat == 2) { W = W_cm; bias = b_cm; vec = c_fin; }
    else               { W = W_cv; bias = b_cv; vec = c_fin; }

    const float* wrow = W + (size_t)l * 1024;
    float acc = 0.0f;
    #pragma unroll
    for (int i = 0; i < 8; ++i) {
        const float4 wv = *(const float4*)(wrow + i * 128 + j * 4);
        const float4 xv = *(const float4*)(vec  + i * 128 + j * 4);
        acc += wv.x * xv.x + wv.y * xv.y + wv.z * xv.z + wv.w * xv.w;
    }
    acc += __shfl_xor(acc, 1);
    acc += __shfl_xor(acc, 2);
    acc += __shfl_xor(acc, 4);
    acc += __shfl_xor(acc, 8);
    acc += __shfl_xor(acc, 16);
    if (j == 0) out[o] = acc + bias[l];
}

// ---------------------------------------------------------------------------
extern "C" void kernel_launch(void* const* d_in, const int* in_sizes, int n_in,
                              void* d_out, int out_size, void* d_ws, size_t ws_size,
                              hipStream_t stream)
{
    const int*   tokens = (const int*)  d_in[0];
    const float* h0     = (const float*)d_in[1];
    const float* c0     = (const float*)d_in[2];
    const float* emb    = (const float*)d_in[3];
    const float* w_ih   = (const float*)d_in[4];
    const float* w_hh   = (const float*)d_in[5];
    const float* b_ih   = (const float*)d_in[6];
    const float* b_hh   = (const float*)d_in[7];
    const float* W_hm   = (const float*)d_in[8];
    const float* b_hm   = (const float*)d_in[9];
    const float* W_hv   = (const float*)d_in[10];
    const float* b_hv   = (const float*)d_in[11];
    const float* W_cm   = (const float*)d_in[12];
    const float* b_cm   = (const float*)d_in[13];
    const float* W_cv   = (const float*)d_in[14];
    const float* b_cv   = (const float*)d_in[15];
    float* out = (float*)d_out;

    char* ws = (char*)d_ws;
    float*              xg    = (float*)ws;            // T*4H fp32 = 64 MB
    size_t              off   = (size_t)T_SEQ * G4 * sizeof(float);
    unsigned long long* h_msg = (unsigned long long*)(ws + off);
    off += 2 * H_DIM * sizeof(unsigned long long);     // 16 KB
    float* h_fin = (float*)(ws + off); off += H_DIM * sizeof(float);
    float* c_fin = (float*)(ws + off); off += H_DIM * sizeof(float);

    // allow 134 KB dynamic LDS for the scan kernel (host attr, capture-safe)
    (void)hipFuncSetAttribute((const void*)lstm_scan,
                              hipFuncAttributeMaxDynamicSharedMemorySize,
                              SCAN_LDS_BYTES);

    // clear stale tags (part of the captured graph => replay-safe)
    hipMemsetAsync(h_msg, 0xFF, 2 * H_DIM * sizeof(unsigned long long), stream);

    xg_gemm<<<dim3(32, 32), 256, 0, stream>>>(tokens, emb, w_ih, b_ih, b_hh, xg);
    lstm_scan<<<NBLK, NTHR, SCAN_LDS_BYTES, stream>>>(xg, w_hh, h0, c0, h_msg,
                                                      h_fin, c_fin);
    proj_kernel<<<128, 256, 0, stream>>>(h_fin, c_fin, W_hm, b_hm, W_hv, b_hv,
                                         W_cm, b_cm, W_cv, b_cv, out);
}

// Round 14
// 7143.288 us; speedup vs baseline: 1.7459x; 1.0138x over previous
//
#include <hip/hip_runtime.h>
#include <math.h>

#define T_SEQ 4096
#define H_DIM 1024
#define G4    4096
#define NBLK  64      // scan blocks; each owns 16 h-lanes (64 gate rows)
#define NTHR  512
// dynamic LDS: 128KB f16 weights + 2KB f16 h + 4KB dot_part[2][8][64]
#define SCAN_LDS_BYTES (131072 + 2048 + 4096)

// __builtin_amdgcn_cvt_pkrtz / fdot2 use the __fp16 vector type (R11 lesson).
typedef __fp16 half2_t __attribute__((ext_vector_type(2)));
union U32H2 { unsigned u; half2_t h; };
__device__ __forceinline__ half2_t as_h2(unsigned u) { U32H2 c; c.u = u; return c.h; }
__device__ __forceinline__ unsigned pkh2(float a, float b) {
    U32H2 c; c.h = __builtin_amdgcn_cvt_pkrtz(a, b); return c.u;
}

// ---------------------------------------------------------------------------
// K1: xg[t][j] = dot(embedding[tokens[t]], w_ih[j]) + b_ih[j] + b_hh[j]
// f16 GEMM via v_dot2_f32_f16: 128x128 tile, BK=16, 256 threads, 8x8
// microtile.  Staging converts fp32->f16 pairs (k-pairs packed in u32).
// ---------------------------------------------------------------------------
__global__ __launch_bounds__(256) void xg_gemm(
    const int* __restrict__ tokens, const float* __restrict__ emb,
    const float* __restrict__ w_ih, const float* __restrict__ b_ih,
    const float* __restrict__ b_hh, float* __restrict__ xg)
{
    __shared__ unsigned As2[8][128];   // [k-pair][row] f16x2
    __shared__ unsigned Bs2[8][128];
    __shared__ int      tk[128];

    const int tid  = threadIdx.x;
    const int row0 = blockIdx.y * 128;
    const int col0 = blockIdx.x * 128;

    if (tid < 128) tk[tid] = tokens[row0 + tid];
    __syncthreads();

    const int r    = tid >> 1;      // staging row 0..127
    const int half = tid & 1;       // staging k-half (8 floats each)
    const int tx   = tid & 15;
    const int ty   = tid >> 4;

    const float* ap_base = emb + (size_t)tk[r] * 1024 + half * 8;
    const float* bp_base = w_ih + (size_t)(col0 + r) * 1024 + half * 8;

    float acc[8][8] = {};

    for (int kc = 0; kc < 1024; kc += 16) {
        const float4 a0 = ((const float4*)(ap_base + kc))[0];
        const float4 a1 = ((const float4*)(ap_base + kc))[1];
        const float4 b0 = ((const float4*)(bp_base + kc))[0];
        const float4 b1 = ((const float4*)(bp_base + kc))[1];
        __syncthreads();   // previous compute finished before overwrite
        const int kb = half * 4;
        As2[kb+0][r] = pkh2(a0.x, a0.y);
        As2[kb+1][r] = pkh2(a0.z, a0.w);
        As2[kb+2][r] = pkh2(a1.x, a1.y);
        As2[kb+3][r] = pkh2(a1.z, a1.w);
        Bs2[kb+0][r] = pkh2(b0.x, b0.y);
        Bs2[kb+1][r] = pkh2(b0.z, b0.w);
        Bs2[kb+2][r] = pkh2(b1.x, b1.y);
        Bs2[kb+3][r] = pkh2(b1.z, b1.w);
        __syncthreads();
        #pragma unroll
        for (int kk = 0; kk < 8; ++kk) {
            unsigned aa[8], bb[8];
            #pragma unroll
            for (int ii = 0; ii < 8; ++ii) aa[ii] = As2[kk][ty*8 + ii];
            #pragma unroll
            for (int jj = 0; jj < 8; ++jj) bb[jj] = Bs2[kk][tx*8 + jj];
            #pragma unroll
            for (int ii = 0; ii < 8; ++ii)
                #pragma unroll
                for (int jj = 0; jj < 8; ++jj)
                    acc[ii][jj] = __builtin_amdgcn_fdot2(
                        as_h2(aa[ii]), as_h2(bb[jj]), acc[ii][jj], false);
        }
    }

    const int ccol = col0 + tx * 8;
    float bs[8];
    #pragma unroll
    for (int jj = 0; jj < 8; ++jj) bs[jj] = b_ih[ccol + jj] + b_hh[ccol + jj];
    #pragma unroll
    for (int ii = 0; ii < 8; ++ii) {
        float* orow = xg + (size_t)(row0 + ty*8 + ii) * G4 + ccol;
        float4 o0, o1;
        o0.x = acc[ii][0] + bs[0]; o0.y = acc[ii][1] + bs[1];
        o0.z = acc[ii][2] + bs[2]; o0.w = acc[ii][3] + bs[3];
        o1.x = acc[ii][4] + bs[4]; o1.y = acc[ii][5] + bs[5];
        o1.z = acc[ii][6] + bs[6]; o1.w = acc[ii][7] + bs[7];
        ((float4*)orow)[0] = o0;
        ((float4*)orow)[1] = o1;
    }
}

// ---------------------------------------------------------------------------
// K2: persistent LSTM scan, wave-sliced.  64 blocks x 512 threads; block b
// owns h-lanes {16b..16b+15} (64 gate rows).  Wave w owns h-chunk
// [128w,128w+128): polls/gathers/stores that chunk, computes every row's
// partial dot against it.  Weights + h in f16 LDS; dot via v_dot2_f32_f16.
// Sync model (R5..R13 synthesis): exchange cost ~1.3-1.4us/step is the
// store->coherence-point->load round trip + max-of-64 arrival jitter; poll
// rate (R12) and replication (R10) don't move it.  R13 removed the sentinel
// hop (-0.22us/step, matched prediction).  This round: f16-PACKED messages
// {tag, 2xf16} -> 8 msgs/publisher, ONE poll load per consumer lane (shorter
// poll period, less jitter); h was already consumed in f16, so no precision
// change.  Tag travels with data; no fences.  2-slot ring, max skew 1 step.
// ---------------------------------------------------------------------------
__device__ __forceinline__ float fsigmoid_(float x) {
    return 1.0f / (1.0f + __expf(-x));
}
__device__ __forceinline__ float ftanh_(float x) {
    x = fminf(fmaxf(x, -10.0f), 10.0f);
    const float e = __expf(2.0f * x);
    return (e - 1.0f) / (e + 1.0f);
}

__global__ __launch_bounds__(NTHR, 1) void lstm_scan(
    const float* __restrict__ xg, const float* __restrict__ w_hh,
    const float* __restrict__ h0, const float* __restrict__ c0,
    unsigned long long* h_msg,           // [2][512] {tag, 2xf16}
    float* __restrict__ h_fin, float* __restrict__ c_fin)
{
    extern __shared__ char smem[];
    unsigned* w_lds = (unsigned*)smem;                    // 32768 u32 (f16 pairs)
    unsigned* hbuf  = (unsigned*)(smem + 131072);         // 512 u32 (1024 f16)
    float*    dpart = (float*)(smem + 131072 + 2048);     // [2][8][64]

    const int tid  = threadIdx.x;
    const int b    = blockIdx.x;
    const int wv   = tid >> 6;           // wave 0..7 = h-chunk index
    const int lane = tid & 63;           // row within block (gate g=lane>>4, m=lane&15)

    // ---- stage weights fp32 -> f16, layout [wv][i][lane] uint4 (lane-consec)
    {
        const int grow = (lane >> 4) * 1024 + 16 * b + (lane & 15);
        const float* wsrc = w_hh + (size_t)grow * 1024 + wv * 128;
        uint4* wdst = (uint4*)w_lds + wv * 1024 + lane;
        #pragma unroll
        for (int i = 0; i < 16; ++i) {
            const float4 a = ((const float4*)wsrc)[2 * i];
            const float4 d = ((const float4*)wsrc)[2 * i + 1];
            uint4 u;
            u.x = pkh2(a.x, a.y); u.y = pkh2(a.z, a.w);
            u.z = pkh2(d.x, d.y); u.w = pkh2(d.z, d.w);
            wdst[i * 64] = u;
        }
    }

    float c_reg = 0.0f;
    if (tid < 16) c_reg = c0[16 * b + tid];
    float xc = 0.0f;
    if (tid < 64) xc = xg[(size_t)(tid >> 4) * 1024 + 16 * b + (tid & 15)];

    // stage h0 chunk (lane owns h values 128wv+2lane, +1)
    {
        const float2 hh = ((const float2*)h0)[wv * 64 + lane];
        hbuf[wv * 64 + lane] = pkh2(hh.x, hh.y);
    }
    __syncthreads();

    const uint4* wrd = (const uint4*)w_lds + wv * 1024 + lane;
    const uint4* h4  = (const uint4*)hbuf + wv * 16;     // chunk = 16 uint4, broadcast

    uint4 wreg[16];
    #pragma unroll
    for (int i = 0; i < 16; ++i) wreg[i] = wrd[i * 64];

    for (int t = 0; t < T_SEQ; ++t) {
        if (t > 0) {
            // merged detect+gather: lane tag-polls its OWN packed msg (1 load)
            const unsigned ver = (unsigned)t;
            const unsigned long long* src =
                h_msg + (size_t)(t & 1) * 512 + 64 * wv + lane;
            unsigned long long v0;
            for (;;) {
                v0 = __hip_atomic_load(src, __ATOMIC_RELAXED, __HIP_MEMORY_SCOPE_AGENT);
                if ((unsigned)(v0 >> 32) == ver) break;
            }
            hbuf[wv * 64 + lane] = (unsigned)v0;   // 2xf16 payload as-is
        }
        // drain LDS writes; same-wave lockstep makes them visible to all lanes
        asm volatile("s_waitcnt lgkmcnt(0)" ::: "memory");
        __builtin_amdgcn_wave_barrier();
        __builtin_amdgcn_sched_barrier(0);

        // 128-MAC partial dot: f16 weights (regs) x f16 h chunk (LDS broadcast)
        float acc = 0.0f;
        #pragma unroll
        for (int i = 0; i < 16; ++i) {
            const uint4 uw = wreg[i];
            const uint4 uh = h4[i];
            acc = __builtin_amdgcn_fdot2(as_h2(uw.x), as_h2(uh.x), acc, false);
            acc = __builtin_amdgcn_fdot2(as_h2(uw.y), as_h2(uh.y), acc, false);
            acc = __builtin_amdgcn_fdot2(as_h2(uw.z), as_h2(uh.z), acc, false);
            acc = __builtin_amdgcn_fdot2(as_h2(uw.w), as_h2(uh.w), acc, false);
        }
        dpart[(t & 1) * 512 + wv * 64 + lane] = acc;

        // reload wreg for next iter (latency hides under barrier+pointwise)
        #pragma unroll
        for (int i = 0; i < 16; ++i) wreg[i] = wrd[i * 64];

        // prefetch next xg (consumed next iteration's pointwise)
        float xn = 0.0f;
        if ((tid < 64) & (t < T_SEQ - 1))
            xn = xg[(size_t)(t + 1) * G4 + (tid >> 4) * 1024 + 16 * b + (tid & 15)];

        __syncthreads();

        // gate-parallel pointwise + packed publish (wave 0); other waves
        // free-run into the next poll (dpart double-buffer makes this safe)
        if (tid < 64) {
            const float* dp = dpart + (t & 1) * 512;
            float x = xc;
            #pragma unroll
            for (int w8 = 0; w8 < 8; ++w8) x += dp[w8 * 64 + tid];
            const float act = ((tid >> 4) == 2) ? ftanh_(x) : fsigmoid_(x);
            const int m = tid & 15;
            const float a_i = __shfl(act, m, 64);
            const float a_f = __shfl(act, m + 16, 64);
            const float a_g = __shfl(act, m + 32, 64);
            const float a_o = __shfl(act, m + 48, 64);
            float hn = 0.0f;
            if (tid < 16) {
                c_reg = a_f * c_reg + a_i * a_g;
                hn = a_o * ftanh_(c_reg);
                if (t == T_SEQ - 1) {
                    h_fin[16 * b + tid] = hn;
                    c_fin[16 * b + tid] = c_reg;
                }
            }
            // pack pairs: lane l<8 publishes {hn[2l], hn[2l+1]} + tag
            const float hv0 = __shfl(hn, 2 * (tid & 7), 64);
            const float hv1 = __shfl(hn, 2 * (tid & 7) + 1, 64);
            if ((tid < 8) & (t < T_SEQ - 1)) {
                const unsigned long long msg =
                    ((unsigned long long)(unsigned)(t + 1) << 32) | pkh2(hv0, hv1);
                __hip_atomic_store(&h_msg[(size_t)((t + 1) & 1) * 512 + 8 * b + tid],
                                   msg, __ATOMIC_RELAXED, __HIP_MEMORY_SCOPE_AGENT);
            }
        }
        xc = xn;
    }
}

// ---------------------------------------------------------------------------
// K3: four 256x1024 mat-vec projections + bias.  One output per 32-lane group.
// ---------------------------------------------------------------------------
__global__ __launch_bounds__(256) void proj_kernel(
    const float* __restrict__ h_fin, const float* __restrict__ c_fin,
    const float* __restrict__ W_hm, const float* __restrict__ b_hm,
    const float* __restrict__ W_hv, const float* __restrict__ b_hv,
    const float* __restrict__ W_cm, const float* __restrict__ b_cm,
    const float* __restrict__ W_cv, const float* __restrict__ b_cv,
    float* __restrict__ out)
{
    const int tid = threadIdx.x;
    const int g32 = tid >> 5;
    const int j   = tid & 31;
    const int o   = blockIdx.x * 8 + g32;   // 0..1023
    const int mat = o >> 8;
    const int l   = o & 255;

    const float* W;  const float* bias;  const float* vec;
    if      (mat == 0) { W = W_hm; bias = b_hm; vec = h_fin; }
    else if (mat == 1) { W = W_hv; bias = b_hv; vec = h_fin; }
    else if (mat == 2) { W = W_cm; bias = b_cm; vec = c_fin; }
    else               { W = W_cv; bias = b_cv; vec = c_fin; }

    const float* wrow = W + (size_t)l * 1024;
    float acc = 0.0f;
    #pragma unroll
    for (int i = 0; i < 8; ++i) {
        const float4 wv = *(const float4*)(wrow + i * 128 + j * 4);
        const float4 xv = *(const float4*)(vec  + i * 128 + j * 4);
        acc += wv.x * xv.x + wv.y * xv.y + wv.z * xv.z + wv.w * xv.w;
    }
    acc += __shfl_xor(acc, 1);
    acc += __shfl_xor(acc, 2);
    acc += __shfl_xor(acc, 4);
    acc += __shfl_xor(acc, 8);
    acc += __shfl_xor(acc, 16);
    if (j == 0) out[o] = acc + bias[l];
}

// ---------------------------------------------------------------------------
extern "C" void kernel_launch(void* const* d_in, const int* in_sizes, int n_in,
                              void* d_out, int out_size, void* d_ws, size_t ws_size,
                              hipStream_t stream)
{
    const int*   tokens = (const int*)  d_in[0];
    const float* h0     = (const float*)d_in[1];
    const float* c0     = (const float*)d_in[2];
    const float* emb    = (const float*)d_in[3];
    const float* w_ih   = (const float*)d_in[4];
    const float* w_hh   = (const float*)d_in[5];
    const float* b_ih   = (const float*)d_in[6];
    const float* b_hh   = (const float*)d_in[7];
    const float* W_hm   = (const float*)d_in[8];
    const float* b_hm   = (const float*)d_in[9];
    const float* W_hv   = (const float*)d_in[10];
    const float* b_hv   = (const float*)d_in[11];
    const float* W_cm   = (const float*)d_in[12];
    const float* b_cm   = (const float*)d_in[13];
    const float* W_cv   = (const float*)d_in[14];
    const float* b_cv   = (const float*)d_in[15];
    float* out = (float*)d_out;

    char* ws = (char*)d_ws;
    float*              xg    = (float*)ws;            // T*4H fp32 = 64 MB
    size_t              off   = (size_t)T_SEQ * G4 * sizeof(float);
    unsigned long long* h_msg = (unsigned long long*)(ws + off);
    off += 2 * 512 * sizeof(unsigned long long);       // 8 KB
    float* h_fin = (float*)(ws + off); off += H_DIM * sizeof(float);
    float* c_fin = (float*)(ws + off); off += H_DIM * sizeof(float);

    // allow 134 KB dynamic LDS for the scan kernel (host attr, capture-safe)
    (void)hipFuncSetAttribute((const void*)lstm_scan,
                              hipFuncAttributeMaxDynamicSharedMemorySize,
                              SCAN_LDS_BYTES);

    // clear stale tags (part of the captured graph => replay-safe)
    hipMemsetAsync(h_msg, 0xFF, 2 * 512 * sizeof(unsigned long long), stream);

    xg_gemm<<<dim3(32, 32), 256, 0, stream>>>(tokens, emb, w_ih, b_ih, b_hh, xg);
    lstm_scan<<<NBLK, NTHR, SCAN_LDS_BYTES, stream>>>(xg, w_hh, h0, c0, h_msg,
                                                      h_fin, c_fin);
    proj_kernel<<<128, 256, 0, stream>>>(h_fin, c_fin, W_hm, b_hm, W_hv, b_hv,
                                         W_cm, b_cm, W_cv, b_cv, out);
}